// Round 4
// baseline (1271.811 us; speedup 1.0000x reference)
//
#include <hip/hip_runtime.h>

typedef _Float16 f16;
typedef _Float16 f16x4 __attribute__((ext_vector_type(4)));
typedef _Float16 f16x8 __attribute__((ext_vector_type(8)));
typedef float f32x4 __attribute__((ext_vector_type(4)));

#define QSCALE 0.08838834764831845f  // DK^-0.5

// ------------------------------------------------------------------
// convert fp32 -> f16 (vectorized x4)
// ------------------------------------------------------------------
__global__ __launch_bounds__(256) void cvt16_kernel(const float* __restrict__ in,
                                                    f16* __restrict__ out, int n4) {
    int i = blockIdx.x * 256 + threadIdx.x;
    if (i >= n4) return;
    f32x4 v = ((const f32x4*)in)[i];
    f16x4 h;
    h[0] = (f16)v[0]; h[1] = (f16)v[1]; h[2] = (f16)v[2]; h[3] = (f16)v[3];
    ((f16x4*)out)[i] = h;
}

// ------------------------------------------------------------------
// transpose fp32 [R][C] -> f16 [C][R]
// ------------------------------------------------------------------
__global__ __launch_bounds__(256) void transpose16_kernel(const float* __restrict__ in,
                                                          f16* __restrict__ out, int R, int C) {
    __shared__ f16 tile[64][66];
    int c0 = blockIdx.x * 64, r0 = blockIdx.y * 64;
    int tid = threadIdx.x;
#pragma unroll
    for (int i = 0; i < 16; ++i) {
        int idx = i * 256 + tid;
        int r = idx >> 6, c = idx & 63;
        tile[r][c] = (f16)in[(long)(r0 + r) * C + (c0 + c)];
    }
    __syncthreads();
#pragma unroll
    for (int i = 0; i < 16; ++i) {
        int idx = i * 256 + tid;
        int orow = idx >> 6, oc = idx & 63;
        out[(long)(c0 + orow) * R + (r0 + oc)] = tile[oc][orow];
    }
}

// ------------------------------------------------------------------
// f16 MFMA GEMM: C[m][n] = sum_k A[m][k] * Bt[n][k]
// 128x128 tile, BK=64, 4 waves (2x2), XOR-swizzled LDS, reg-staged.
// ------------------------------------------------------------------
template <int F16OUT>
__global__ __launch_bounds__(256) void gemm16_kernel(const f16* __restrict__ A,
                                                     const f16* __restrict__ Bt,
                                                     void* __restrict__ Cout,
                                                     int M, int N, int Kd) {
    __shared__ f16 sA[128 * 64];
    __shared__ f16 sB[128 * 64];
    const int tid = threadIdx.x;
    const int lane = tid & 63, wv = tid >> 6;
    const int wm = wv >> 1, wn = wv & 1;
    const int m0 = blockIdx.y * 128, n0 = blockIdx.x * 128;
    const int lrow = lane & 15, lk = lane >> 4;
    f32x4 acc[4][4] = {};
    for (int k0 = 0; k0 < Kd; k0 += 64) {
        __syncthreads();
#pragma unroll
        for (int j = 0; j < 4; ++j) {
            int P = (tid + j * 256) * 16;
            int row = P >> 7;
            int sw = P ^ ((row & 7) << 4);
            int koff = P & 127;
            const char* ga = (const char*)(A + (long)(m0 + row) * Kd + k0) + koff;
            *(f32x4*)((char*)sA + sw) = *(const f32x4*)ga;
            const char* gb = (const char*)(Bt + (long)(n0 + row) * Kd + k0) + koff;
            *(f32x4*)((char*)sB + sw) = *(const f32x4*)gb;
        }
        __syncthreads();
#pragma unroll
        for (int kk = 0; kk < 2; ++kk) {
            f16x8 af[4], bf[4];
#pragma unroll
            for (int i = 0; i < 4; ++i) {
                int arow = wm * 64 + i * 16 + lrow;
                int abyte = arow * 128 + kk * 64 + lk * 16;
                af[i] = *(const f16x8*)((const char*)sA + (abyte ^ ((arow & 7) << 4)));
                int brow = wn * 64 + i * 16 + lrow;
                int bbyte = brow * 128 + kk * 64 + lk * 16;
                bf[i] = *(const f16x8*)((const char*)sB + (bbyte ^ ((brow & 7) << 4)));
            }
#pragma unroll
            for (int i = 0; i < 4; ++i)
#pragma unroll
                for (int j = 0; j < 4; ++j)
                    acc[i][j] = __builtin_amdgcn_mfma_f32_16x16x32_f16(af[i], bf[j], acc[i][j], 0, 0, 0);
        }
    }
#pragma unroll
    for (int i = 0; i < 4; ++i) {
        int gm_base = m0 + wm * 64 + i * 16 + lk * 4;
#pragma unroll
        for (int j = 0; j < 4; ++j) {
            int gn = n0 + wn * 64 + j * 16 + lrow;
#pragma unroll
            for (int r = 0; r < 4; ++r) {
                long idx = (long)(gm_base + r) * N + gn;
                if (F16OUT) ((f16*)Cout)[idx] = (f16)acc[i][j][r];
                else        ((float*)Cout)[idx] = acc[i][j][r];
            }
        }
    }
}

// ------------------------------------------------------------------
// ba = x @ w_ba   (fp32)
// ------------------------------------------------------------------
__global__ __launch_bounds__(256) void ba_gemm_kernel(const float* __restrict__ x,
                                                      const float* __restrict__ w,
                                                      float* __restrict__ ba) {
    __shared__ float xs[16][256];
    int tid = threadIdx.x;
    int t0 = blockIdx.x * 16;
    int o = tid & 63, tg = tid >> 6;
    float acc[4] = {0.f, 0.f, 0.f, 0.f};
    for (int kc = 0; kc < 2048; kc += 256) {
        __syncthreads();
#pragma unroll
        for (int i = 0; i < 16; ++i) {
            int idx = i * 256 + tid;
            int tok = idx >> 8, k = idx & 255;
            xs[tok][k] = x[(long)(t0 + tok) * 2048 + kc + k];
        }
        __syncthreads();
        for (int k = 0; k < 256; ++k) {
            float wv = w[(long)(kc + k) * 64 + o];
#pragma unroll
            for (int j = 0; j < 4; ++j) acc[j] += xs[tg * 4 + j][k] * wv;
        }
    }
#pragma unroll
    for (int j = 0; j < 4; ++j) ba[(long)(t0 + tg * 4 + j) * 64 + o] = acc[j];
}

// ------------------------------------------------------------------
// depthwise causal conv(K=4) + bias + SiLU (+ L2norm for q/k heads)
// ------------------------------------------------------------------
__global__ __launch_bounds__(256) void conv_kernel(const f16* __restrict__ qkvz,
                                                   const float* __restrict__ cw,
                                                   const float* __restrict__ cb,
                                                   f16* __restrict__ qh,
                                                   f16* __restrict__ kh,
                                                   f16* __restrict__ vh) {
    __shared__ float Lin[35 * 128];
    __shared__ float Lout[32 * 128];
    __shared__ float Lsc[32];
    int g = blockIdx.x;
    int s0 = blockIdx.y * 32;
    int b = blockIdx.z;
    int tid = threadIdx.x;
    int colbase, chbase;
    f16* outp;
    bool donorm;
    float nmul;
    if (g < 16) {
        colbase = g * 768; chbase = g * 128;
        outp = qh + (((long)b * 16 + g) * 2048 + s0) * 128;
        donorm = true; nmul = QSCALE;
    } else if (g < 32) {
        int hk = g - 16;
        colbase = hk * 768 + 128; chbase = 2048 + hk * 128;
        outp = kh + (((long)b * 16 + hk) * 2048 + s0) * 128;
        donorm = true; nmul = 1.f;
    } else {
        int hv = g - 32;
        colbase = (hv >> 1) * 768 + 256 + (hv & 1) * 128; chbase = 4096 + hv * 128;
        outp = vh + (((long)b * 32 + hv) * 2048 + s0) * 128;
        donorm = false; nmul = 1.f;
    }
    for (int idx = tid; idx < 35 * 128; idx += 256) {
        int sr = idx >> 7, c = idx & 127;
        int s = s0 + sr - 3;
        Lin[idx] = (s >= 0) ? (float)qkvz[((long)b * 2048 + s) * 12288 + colbase + c] : 0.f;
    }
    __syncthreads();
    int c = tid & 127, sg = tid >> 7;
    float w0 = cw[(chbase + c) * 4 + 0];
    float w1 = cw[(chbase + c) * 4 + 1];
    float w2 = cw[(chbase + c) * 4 + 2];
    float w3 = cw[(chbase + c) * 4 + 3];
    float bias = cb[chbase + c];
#pragma unroll
    for (int j = 0; j < 16; ++j) {
        int sl = sg * 16 + j;
        float v = w0 * Lin[sl * 128 + c] + w1 * Lin[(sl + 1) * 128 + c] +
                  w2 * Lin[(sl + 2) * 128 + c] + w3 * Lin[(sl + 3) * 128 + c] + bias;
        v = v / (1.f + expf(-v));  // SiLU
        Lout[sl * 128 + c] = v;
    }
    __syncthreads();
    if (donorm) {
        int token = tid >> 3, part = tid & 7;
        float ss = 0.f;
#pragma unroll
        for (int i = 0; i < 16; ++i) {
            float v = Lout[token * 128 + part * 16 + i];
            ss += v * v;
        }
        ss += __shfl_xor(ss, 1); ss += __shfl_xor(ss, 2); ss += __shfl_xor(ss, 4);
        if (part == 0) Lsc[token] = rsqrtf(ss + 1e-6f) * nmul;
        __syncthreads();
#pragma unroll
        for (int j = 0; j < 16; ++j) {
            int sl = sg * 16 + j;
            outp[(long)sl * 128 + c] = (f16)(Lout[sl * 128 + c] * Lsc[sl]);
        }
    } else {
#pragma unroll
        for (int j = 0; j < 16; ++j) {
            int sl = sg * 16 + j;
            outp[(long)sl * 128 + c] = (f16)Lout[sl * 128 + c];
        }
    }
}

// ------------------------------------------------------------------
// eg = exp(g), beta = sigmoid(b)
// ------------------------------------------------------------------
__global__ __launch_bounds__(256) void gb_kernel(const float* __restrict__ ba,
                                                 const float* __restrict__ a_log,
                                                 const float* __restrict__ dt_bias,
                                                 float* __restrict__ eg,
                                                 float* __restrict__ bt) {
    int idx = blockIdx.x * 256 + threadIdx.x;  // ((b*32+hv)*2048 + s)
    if (idx >= 2 * 32 * 2048) return;
    int s = idx & 2047;
    int hv = (idx >> 11) & 31;
    int b = idx >> 16;
    int gg = hv & 1, hk = hv >> 1;
    long base = ((long)b * 2048 + s) * 64 + hk * 4;
    float bv = ba[base + gg];
    float av = ba[base + 2 + gg];
    float xx = av + dt_bias[hv];
    float sp = (xx > 20.f) ? xx : log1pf(expf(xx));
    float gv = -expf(a_log[hv]) * sp;
    eg[idx] = expf(gv);
    bt[idx] = 1.f / (1.f + expf(-bv));
}

// ------------------------------------------------------------------
// three interleaved 16-lane row sums via DPP row_ror (latency-overlapped)
// ------------------------------------------------------------------
__device__ __forceinline__ void rowsum16x3(float& a, float& b, float& c) {
    int va, vb, vc;
    va = __float_as_int(a); vb = __float_as_int(b); vc = __float_as_int(c);
    a += __int_as_float(__builtin_amdgcn_update_dpp(va, va, 0x121, 0xF, 0xF, false));
    b += __int_as_float(__builtin_amdgcn_update_dpp(vb, vb, 0x121, 0xF, 0xF, false));
    c += __int_as_float(__builtin_amdgcn_update_dpp(vc, vc, 0x121, 0xF, 0xF, false));
    va = __float_as_int(a); vb = __float_as_int(b); vc = __float_as_int(c);
    a += __int_as_float(__builtin_amdgcn_update_dpp(va, va, 0x122, 0xF, 0xF, false));
    b += __int_as_float(__builtin_amdgcn_update_dpp(vb, vb, 0x122, 0xF, 0xF, false));
    c += __int_as_float(__builtin_amdgcn_update_dpp(vc, vc, 0x122, 0xF, 0xF, false));
    va = __float_as_int(a); vb = __float_as_int(b); vc = __float_as_int(c);
    a += __int_as_float(__builtin_amdgcn_update_dpp(va, va, 0x124, 0xF, 0xF, false));
    b += __int_as_float(__builtin_amdgcn_update_dpp(vb, vb, 0x124, 0xF, 0xF, false));
    c += __int_as_float(__builtin_amdgcn_update_dpp(vc, vc, 0x124, 0xF, 0xF, false));
    va = __float_as_int(a); vb = __float_as_int(b); vc = __float_as_int(c);
    a += __int_as_float(__builtin_amdgcn_update_dpp(va, va, 0x128, 0xF, 0xF, false));
    b += __int_as_float(__builtin_amdgcn_update_dpp(vb, vb, 0x128, 0xF, 0xF, false));
    c += __int_as_float(__builtin_amdgcn_update_dpp(vc, vc, 0x128, 0xF, 0xF, false));
}

// ------------------------------------------------------------------
// sequential gated delta scan, chunked LDS staging (f32 in LDS),
// de-serialized step:
//   A1=k.S, A2=q.S, A3=q.k (3 independent chains) -> rowsum x3 ->
//   dv = b(v - e*A1); po = e*A2 + A3*dv; S = e*S + k*dv.
// block: 512 threads = 32 cols x 16 dkg; grid 256 = (b, hv, vs in [0,4))
// ------------------------------------------------------------------
#define CH 32  // steps per staged chunk

struct StepRegs {
    f32x4 kA, kB, qA, qB;
    float v, e, b;
};

__global__ __launch_bounds__(512) void scan_kernel(const f16* __restrict__ qh,
                                                   const f16* __restrict__ kh,
                                                   const f16* __restrict__ vh,
                                                   const float* __restrict__ eg,
                                                   const float* __restrict__ bt,
                                                   float* __restrict__ o) {
    __shared__ float Lk[CH * 128];
    __shared__ float Lq[CH * 128];
    __shared__ float Lv[CH * 32];
    __shared__ float Leg[CH];
    __shared__ float Lbt[CH];

    int bid = blockIdx.x;
    int vs = bid & 3;
    int hv = (bid >> 2) & 31;
    int b = bid >> 7;
    int tid = threadIdx.x;
    int col = tid >> 4, dkg = tid & 15;
    int vcol = vs * 32 + col;
    const f16* kp = kh + ((long)b * 16 + (hv >> 1)) * 2048 * 128;
    const f16* qp = qh + ((long)b * 16 + (hv >> 1)) * 2048 * 128;
    const f16* vp = vh + ((long)b * 32 + hv) * 2048 * 128;
    const float* egp = eg + ((long)b * 32 + hv) * 2048;
    const float* btp = bt + ((long)b * 32 + hv) * 2048;
    float* op = o + ((long)b * 2048 * 32 + hv) * 128 + vcol;

    // staging registers (chunk of CH steps, cooperatively loaded)
    f16x8 rk, rq, rv;
    float re = 0.f, rb = 0.f;
    const int vstep = tid >> 2, vpart = tid & 3;  // for v staging (tid<128)

    auto issue_loads = [&](int c) {
        long base = (long)c * CH * 128;
        rk = *(const f16x8*)(kp + base + tid * 8);
        rq = *(const f16x8*)(qp + base + tid * 8);
        if (tid < 128) rv = *(const f16x8*)(vp + base + vstep * 128 + vs * 32 + vpart * 8);
        if (tid < CH) re = egp[c * CH + tid];
        else if (tid < 2 * CH) rb = btp[c * CH + (tid - CH)];
    };
    auto commit = [&]() {
        f32x4 lo, hi;
#pragma unroll
        for (int i = 0; i < 4; ++i) { lo[i] = (float)rk[i]; hi[i] = (float)rk[4 + i]; }
        ((f32x4*)Lk)[tid * 2] = lo;
        ((f32x4*)Lk)[tid * 2 + 1] = hi;
#pragma unroll
        for (int i = 0; i < 4; ++i) { lo[i] = (float)rq[i]; hi[i] = (float)rq[4 + i]; }
        ((f32x4*)Lq)[tid * 2] = lo;
        ((f32x4*)Lq)[tid * 2 + 1] = hi;
        if (tid < 128) {
#pragma unroll
            for (int i = 0; i < 4; ++i) { lo[i] = (float)rv[i]; hi[i] = (float)rv[4 + i]; }
            ((f32x4*)Lv)[tid * 2] = lo;
            ((f32x4*)Lv)[tid * 2 + 1] = hi;
        }
        if (tid < CH) Leg[tid] = re;
        else if (tid < 2 * CH) Lbt[tid - CH] = rb;
    };

    float St[8] = {0.f, 0.f, 0.f, 0.f, 0.f, 0.f, 0.f, 0.f};

    auto lds_ld = [&](int s, StepRegs& r) {
        const f32x4* kb = (const f32x4*)(Lk + s * 128 + dkg * 8);
        const f32x4* qb = (const f32x4*)(Lq + s * 128 + dkg * 8);
        r.kA = kb[0]; r.kB = kb[1];
        r.qA = qb[0]; r.qB = qb[1];
        r.v = Lv[s * 32 + col];
        r.e = Leg[s];
        r.b = Lbt[s];
    };
    auto do_step = [&](const StepRegs& L, int s) {
        float kf[8] = {L.kA[0], L.kA[1], L.kA[2], L.kA[3], L.kB[0], L.kB[1], L.kB[2], L.kB[3]};
        float qf[8] = {L.qA[0], L.qA[1], L.qA[2], L.qA[3], L.qB[0], L.qB[1], L.qB[2], L.qB[3]};
        float A1 = 0.f, A2 = 0.f, A3 = 0.f;
#pragma unroll
        for (int i = 0; i < 8; ++i) {
            A1 = fmaf(kf[i], St[i], A1);
            A2 = fmaf(qf[i], St[i], A2);
            A3 = fmaf(qf[i], kf[i], A3);
        }
        rowsum16x3(A1, A2, A3);
        float e = L.e;
        float dv = L.b * (L.v - e * A1);
        float po = fmaf(A3, dv, e * A2);
#pragma unroll
        for (int i = 0; i < 8; ++i) St[i] = fmaf(e, St[i], kf[i] * dv);
        if (dkg == 0) op[(long)s * 4096] = po;
    };

    // prologue: stage chunk 0
    issue_loads(0);
    commit();
    __syncthreads();

    for (int c = 0; c < 2048 / CH; ++c) {
        if (c + 1 < 2048 / CH) issue_loads(c + 1);  // in flight during compute
        StepRegs A, Bv;
        lds_ld(0, A);
        for (int s = 0; s < CH; s += 2) {
            lds_ld(s + 1, Bv);
            do_step(A, c * CH + s);
            if (s + 2 < CH) lds_ld(s + 2, A);
            do_step(Bv, c * CH + s + 1);
        }
        __syncthreads();  // all waves done reading LDS
        if (c + 1 < 2048 / CH) commit();
        __syncthreads();
    }
}

// ------------------------------------------------------------------
// y = rmsnorm(o * silu(z)) * norm_w  -> f16
// ------------------------------------------------------------------
__global__ __launch_bounds__(256) void gate_kernel(const float* __restrict__ o,
                                                   const f16* __restrict__ qkvz,
                                                   const float* __restrict__ norm_w,
                                                   f16* __restrict__ y) {
    int token = blockIdx.x;  // b*2048 + s
    int tid = threadIdx.x;
    int hv = tid >> 3, part = tid & 7;
    int dv0 = part * 16;
    const float* orow = o + ((long)token * 32 + hv) * 128 + dv0;
    long zcol = (long)(hv >> 1) * 768 + 512 + (hv & 1) * 128 + dv0;
    const f16* zrow = qkvz + (long)token * 12288 + zcol;
    float yv[16];
    float ss = 0.f;
#pragma unroll
    for (int i = 0; i < 16; ++i) {
        float ov = orow[i];
        float zv = (float)zrow[i];
        float gt = zv / (1.f + expf(-zv));
        float v = ov * gt;
        yv[i] = v;
        ss += v * v;
    }
    ss += __shfl_xor(ss, 1); ss += __shfl_xor(ss, 2); ss += __shfl_xor(ss, 4);
    float scale = rsqrtf(ss * (1.f / 128.f) + 1e-6f);
    f16* yrow = y + (long)token * 4096 + hv * 128 + dv0;
#pragma unroll
    for (int i = 0; i < 16; ++i) yrow[i] = (f16)(yv[i] * scale * norm_w[dv0 + i]);
}

// ------------------------------------------------------------------
// Workspace layout (242 MB total, time-aliased by live range):
//   [0,96)    qkvz16                 (gemm1 -> gate)
//   [96,160)  x16(16)+WT(48)         (prep -> gemm1), then ob f32 (scan -> gate)
//   [160,176) WTo                    (prep -> gemm2)
//   [176,240) qh(16) kh(16) vh(32)   (conv -> scan), first 32 reused as y16 (gate -> gemm2)
//   [240,242) bab / egb / btb
// ------------------------------------------------------------------
extern "C" void kernel_launch(void* const* d_in, const int* in_sizes, int n_in,
                              void* d_out, int out_size, void* d_ws, size_t ws_size,
                              hipStream_t stream) {
    const float* x       = (const float*)d_in[0];
    const float* w_qkvz  = (const float*)d_in[1];
    const float* w_ba    = (const float*)d_in[2];
    const float* conv_w  = (const float*)d_in[3];
    const float* conv_b  = (const float*)d_in[4];
    const float* a_log   = (const float*)d_in[5];
    const float* dt_bias = (const float*)d_in[6];
    const float* norm_w  = (const float*)d_in[7];
    const float* w_o     = (const float*)d_in[8];
    float* out = (float*)d_out;

    char* ws = (char*)d_ws;
    const size_t MB = 1024 * 1024;
    f16*   qkvz16 = (f16*)ws;                      // 96 MB
    f16*   x16    = (f16*)(ws + 96 * MB);          // 16 MB  } aliased by ob
    f16*   WT     = (f16*)(ws + 112 * MB);         // 48 MB  }
    float* ob     = (float*)(ws + 96 * MB);        // 64 MB (after gemm1)
    f16*   WTo    = (f16*)(ws + 160 * MB);         // 16 MB
    f16*   qh     = (f16*)(ws + 176 * MB);         // 16 MB  } first 32 MB aliased by y16
    f16*   kh     = (f16*)(ws + 192 * MB);         // 16 MB  }
    f16*   vh     = (f16*)(ws + 208 * MB);         // 32 MB
    f16*   y16    = (f16*)(ws + 176 * MB);         // 32 MB (after scan)
    float* bab    = (float*)(ws + 240 * MB);       // 1 MB
    float* egb    = (float*)(ws + 241 * MB);       // 0.5 MB
    float* btb    = (float*)(ws + 241 * MB + 512 * 1024);  // 0.5 MB

    // prep: convert / transpose weights & activations
    cvt16_kernel<<<8192, 256, 0, stream>>>(x, x16, 4096 * 2048 / 4);
    transpose16_kernel<<<dim3(12288 / 64, 2048 / 64), 256, 0, stream>>>(w_qkvz, WT, 2048, 12288);
    transpose16_kernel<<<dim3(2048 / 64, 4096 / 64), 256, 0, stream>>>(w_o, WTo, 4096, 2048);

    // qkvz = x @ w_qkvz   (f16 MFMA, f16 out)
    gemm16_kernel<1><<<dim3(12288 / 128, 4096 / 128), 256, 0, stream>>>(x16, WT, qkvz16, 4096, 12288, 2048);
    // ba = x @ w_ba (fp32)
    ba_gemm_kernel<<<256, 256, 0, stream>>>(x, w_ba, bab);

    // conv + silu + l2norm  (f16 out)
    conv_kernel<<<dim3(64, 64, 2), 256, 0, stream>>>(qkvz16, conv_w, conv_b, qh, kh, vh);
    // gate scalars
    gb_kernel<<<512, 256, 0, stream>>>(bab, a_log, dt_bias, egb, btb);

    // sequential delta-rule scan (writes ob over dead x16/WT)
    scan_kernel<<<256, 512, 0, stream>>>(qh, kh, vh, egb, btb, ob);

    // gating + rmsnorm -> y16 (over dead qh/kh)
    gate_kernel<<<4096, 256, 0, stream>>>(ob, qkvz16, norm_w, y16);

    // out = y @ w_o  (f16 MFMA, f32 out)
    gemm16_kernel<0><<<dim3(2048 / 128, 4096 / 128), 256, 0, stream>>>(y16, WTo, out, 4096, 2048, 4096);
}

// Round 5
// 1162.270 us; speedup vs baseline: 1.0942x; 1.0942x over previous
//
#include <hip/hip_runtime.h>

typedef _Float16 f16;
typedef _Float16 f16x4 __attribute__((ext_vector_type(4)));
typedef _Float16 f16x8 __attribute__((ext_vector_type(8)));
typedef float f32x4 __attribute__((ext_vector_type(4)));

#define QSCALE 0.08838834764831845f  // DK^-0.5

// ------------------------------------------------------------------
// convert fp32 -> f16 (vectorized x4)
// ------------------------------------------------------------------
__global__ __launch_bounds__(256) void cvt16_kernel(const float* __restrict__ in,
                                                    f16* __restrict__ out, int n4) {
    int i = blockIdx.x * 256 + threadIdx.x;
    if (i >= n4) return;
    f32x4 v = ((const f32x4*)in)[i];
    f16x4 h;
    h[0] = (f16)v[0]; h[1] = (f16)v[1]; h[2] = (f16)v[2]; h[3] = (f16)v[3];
    ((f16x4*)out)[i] = h;
}

// ------------------------------------------------------------------
// transpose fp32 [R][C] -> f16 [C][R]
// ------------------------------------------------------------------
__global__ __launch_bounds__(256) void transpose16_kernel(const float* __restrict__ in,
                                                          f16* __restrict__ out, int R, int C) {
    __shared__ f16 tile[64][66];
    int c0 = blockIdx.x * 64, r0 = blockIdx.y * 64;
    int tid = threadIdx.x;
#pragma unroll
    for (int i = 0; i < 16; ++i) {
        int idx = i * 256 + tid;
        int r = idx >> 6, c = idx & 63;
        tile[r][c] = (f16)in[(long)(r0 + r) * C + (c0 + c)];
    }
    __syncthreads();
#pragma unroll
    for (int i = 0; i < 16; ++i) {
        int idx = i * 256 + tid;
        int orow = idx >> 6, oc = idx & 63;
        out[(long)(c0 + orow) * R + (r0 + oc)] = tile[oc][orow];
    }
}

// ------------------------------------------------------------------
// f16 MFMA GEMM: C[m][n] = sum_k A[m][k] * Bt[n][k]
// 128x128 tile, BK=64, 4 waves (2x2), XOR-swizzled LDS, reg-staged.
// ------------------------------------------------------------------
template <int F16OUT>
__global__ __launch_bounds__(256) void gemm16_kernel(const f16* __restrict__ A,
                                                     const f16* __restrict__ Bt,
                                                     void* __restrict__ Cout,
                                                     int M, int N, int Kd) {
    __shared__ f16 sA[128 * 64];
    __shared__ f16 sB[128 * 64];
    const int tid = threadIdx.x;
    const int lane = tid & 63, wv = tid >> 6;
    const int wm = wv >> 1, wn = wv & 1;
    const int m0 = blockIdx.y * 128, n0 = blockIdx.x * 128;
    const int lrow = lane & 15, lk = lane >> 4;
    f32x4 acc[4][4] = {};
    for (int k0 = 0; k0 < Kd; k0 += 64) {
        __syncthreads();
#pragma unroll
        for (int j = 0; j < 4; ++j) {
            int P = (tid + j * 256) * 16;
            int row = P >> 7;
            int sw = P ^ ((row & 7) << 4);
            int koff = P & 127;
            const char* ga = (const char*)(A + (long)(m0 + row) * Kd + k0) + koff;
            *(f32x4*)((char*)sA + sw) = *(const f32x4*)ga;
            const char* gb = (const char*)(Bt + (long)(n0 + row) * Kd + k0) + koff;
            *(f32x4*)((char*)sB + sw) = *(const f32x4*)gb;
        }
        __syncthreads();
#pragma unroll
        for (int kk = 0; kk < 2; ++kk) {
            f16x8 af[4], bf[4];
#pragma unroll
            for (int i = 0; i < 4; ++i) {
                int arow = wm * 64 + i * 16 + lrow;
                int abyte = arow * 128 + kk * 64 + lk * 16;
                af[i] = *(const f16x8*)((const char*)sA + (abyte ^ ((arow & 7) << 4)));
                int brow = wn * 64 + i * 16 + lrow;
                int bbyte = brow * 128 + kk * 64 + lk * 16;
                bf[i] = *(const f16x8*)((const char*)sB + (bbyte ^ ((brow & 7) << 4)));
            }
#pragma unroll
            for (int i = 0; i < 4; ++i)
#pragma unroll
                for (int j = 0; j < 4; ++j)
                    acc[i][j] = __builtin_amdgcn_mfma_f32_16x16x32_f16(af[i], bf[j], acc[i][j], 0, 0, 0);
        }
    }
#pragma unroll
    for (int i = 0; i < 4; ++i) {
        int gm_base = m0 + wm * 64 + i * 16 + lk * 4;
#pragma unroll
        for (int j = 0; j < 4; ++j) {
            int gn = n0 + wn * 64 + j * 16 + lrow;
#pragma unroll
            for (int r = 0; r < 4; ++r) {
                long idx = (long)(gm_base + r) * N + gn;
                if (F16OUT) ((f16*)Cout)[idx] = (f16)acc[i][j][r];
                else        ((float*)Cout)[idx] = acc[i][j][r];
            }
        }
    }
}

// ------------------------------------------------------------------
// ba = x @ w_ba   (fp32)
// ------------------------------------------------------------------
__global__ __launch_bounds__(256) void ba_gemm_kernel(const float* __restrict__ x,
                                                      const float* __restrict__ w,
                                                      float* __restrict__ ba) {
    __shared__ float xs[16][256];
    int tid = threadIdx.x;
    int t0 = blockIdx.x * 16;
    int o = tid & 63, tg = tid >> 6;
    float acc[4] = {0.f, 0.f, 0.f, 0.f};
    for (int kc = 0; kc < 2048; kc += 256) {
        __syncthreads();
#pragma unroll
        for (int i = 0; i < 16; ++i) {
            int idx = i * 256 + tid;
            int tok = idx >> 8, k = idx & 255;
            xs[tok][k] = x[(long)(t0 + tok) * 2048 + kc + k];
        }
        __syncthreads();
        for (int k = 0; k < 256; ++k) {
            float wv = w[(long)(kc + k) * 64 + o];
#pragma unroll
            for (int j = 0; j < 4; ++j) acc[j] += xs[tg * 4 + j][k] * wv;
        }
    }
#pragma unroll
    for (int j = 0; j < 4; ++j) ba[(long)(t0 + tg * 4 + j) * 64 + o] = acc[j];
}

// ------------------------------------------------------------------
// depthwise causal conv(K=4) + bias + SiLU (+ L2norm for q/k heads)
// ------------------------------------------------------------------
__global__ __launch_bounds__(256) void conv_kernel(const f16* __restrict__ qkvz,
                                                   const float* __restrict__ cw,
                                                   const float* __restrict__ cb,
                                                   f16* __restrict__ qh,
                                                   f16* __restrict__ kh,
                                                   f16* __restrict__ vh) {
    __shared__ float Lin[35 * 128];
    __shared__ float Lout[32 * 128];
    __shared__ float Lsc[32];
    int g = blockIdx.x;
    int s0 = blockIdx.y * 32;
    int b = blockIdx.z;
    int tid = threadIdx.x;
    int colbase, chbase;
    f16* outp;
    bool donorm;
    float nmul;
    if (g < 16) {
        colbase = g * 768; chbase = g * 128;
        outp = qh + (((long)b * 16 + g) * 2048 + s0) * 128;
        donorm = true; nmul = QSCALE;
    } else if (g < 32) {
        int hk = g - 16;
        colbase = hk * 768 + 128; chbase = 2048 + hk * 128;
        outp = kh + (((long)b * 16 + hk) * 2048 + s0) * 128;
        donorm = true; nmul = 1.f;
    } else {
        int hv = g - 32;
        colbase = (hv >> 1) * 768 + 256 + (hv & 1) * 128; chbase = 4096 + hv * 128;
        outp = vh + (((long)b * 32 + hv) * 2048 + s0) * 128;
        donorm = false; nmul = 1.f;
    }
    for (int idx = tid; idx < 35 * 128; idx += 256) {
        int sr = idx >> 7, c = idx & 127;
        int s = s0 + sr - 3;
        Lin[idx] = (s >= 0) ? (float)qkvz[((long)b * 2048 + s) * 12288 + colbase + c] : 0.f;
    }
    __syncthreads();
    int c = tid & 127, sg = tid >> 7;
    float w0 = cw[(chbase + c) * 4 + 0];
    float w1 = cw[(chbase + c) * 4 + 1];
    float w2 = cw[(chbase + c) * 4 + 2];
    float w3 = cw[(chbase + c) * 4 + 3];
    float bias = cb[chbase + c];
#pragma unroll
    for (int j = 0; j < 16; ++j) {
        int sl = sg * 16 + j;
        float v = w0 * Lin[sl * 128 + c] + w1 * Lin[(sl + 1) * 128 + c] +
                  w2 * Lin[(sl + 2) * 128 + c] + w3 * Lin[(sl + 3) * 128 + c] + bias;
        v = v / (1.f + expf(-v));  // SiLU
        Lout[sl * 128 + c] = v;
    }
    __syncthreads();
    if (donorm) {
        int token = tid >> 3, part = tid & 7;
        float ss = 0.f;
#pragma unroll
        for (int i = 0; i < 16; ++i) {
            float v = Lout[token * 128 + part * 16 + i];
            ss += v * v;
        }
        ss += __shfl_xor(ss, 1); ss += __shfl_xor(ss, 2); ss += __shfl_xor(ss, 4);
        if (part == 0) Lsc[token] = rsqrtf(ss + 1e-6f) * nmul;
        __syncthreads();
#pragma unroll
        for (int j = 0; j < 16; ++j) {
            int sl = sg * 16 + j;
            outp[(long)sl * 128 + c] = (f16)(Lout[sl * 128 + c] * Lsc[sl]);
        }
    } else {
#pragma unroll
        for (int j = 0; j < 16; ++j) {
            int sl = sg * 16 + j;
            outp[(long)sl * 128 + c] = (f16)Lout[sl * 128 + c];
        }
    }
}

// ------------------------------------------------------------------
// eg = exp(g), beta = sigmoid(b)
// ------------------------------------------------------------------
__global__ __launch_bounds__(256) void gb_kernel(const float* __restrict__ ba,
                                                 const float* __restrict__ a_log,
                                                 const float* __restrict__ dt_bias,
                                                 float* __restrict__ eg,
                                                 float* __restrict__ bt) {
    int idx = blockIdx.x * 256 + threadIdx.x;  // ((b*32+hv)*2048 + s)
    if (idx >= 2 * 32 * 2048) return;
    int s = idx & 2047;
    int hv = (idx >> 11) & 31;
    int b = idx >> 16;
    int gg = hv & 1, hk = hv >> 1;
    long base = ((long)b * 2048 + s) * 64 + hk * 4;
    float bv = ba[base + gg];
    float av = ba[base + 2 + gg];
    float xx = av + dt_bias[hv];
    float sp = (xx > 20.f) ? xx : log1pf(expf(xx));
    float gv = -expf(a_log[hv]) * sp;
    eg[idx] = expf(gv);
    bt[idx] = 1.f / (1.f + expf(-bv));
}

// ------------------------------------------------------------------
// 16-lane DPP row sums
// ------------------------------------------------------------------
__device__ __forceinline__ float rowsum16(float x) {
    int v;
    v = __float_as_int(x);
    x += __int_as_float(__builtin_amdgcn_update_dpp(v, v, 0x121, 0xF, 0xF, false));
    v = __float_as_int(x);
    x += __int_as_float(__builtin_amdgcn_update_dpp(v, v, 0x122, 0xF, 0xF, false));
    v = __float_as_int(x);
    x += __int_as_float(__builtin_amdgcn_update_dpp(v, v, 0x124, 0xF, 0xF, false));
    v = __float_as_int(x);
    x += __int_as_float(__builtin_amdgcn_update_dpp(v, v, 0x128, 0xF, 0xF, false));
    return x;
}
__device__ __forceinline__ void rowsum16x2(float& a, float& b) {
    int va, vb;
    va = __float_as_int(a); vb = __float_as_int(b);
    a += __int_as_float(__builtin_amdgcn_update_dpp(va, va, 0x121, 0xF, 0xF, false));
    b += __int_as_float(__builtin_amdgcn_update_dpp(vb, vb, 0x121, 0xF, 0xF, false));
    va = __float_as_int(a); vb = __float_as_int(b);
    a += __int_as_float(__builtin_amdgcn_update_dpp(va, va, 0x122, 0xF, 0xF, false));
    b += __int_as_float(__builtin_amdgcn_update_dpp(vb, vb, 0x122, 0xF, 0xF, false));
    va = __float_as_int(a); vb = __float_as_int(b);
    a += __int_as_float(__builtin_amdgcn_update_dpp(va, va, 0x124, 0xF, 0xF, false));
    b += __int_as_float(__builtin_amdgcn_update_dpp(vb, vb, 0x124, 0xF, 0xF, false));
    va = __float_as_int(a); vb = __float_as_int(b);
    a += __int_as_float(__builtin_amdgcn_update_dpp(va, va, 0x128, 0xF, 0xF, false));
    b += __int_as_float(__builtin_amdgcn_update_dpp(vb, vb, 0x128, 0xF, 0xF, false));
}

// ------------------------------------------------------------------
// qk[b*16+hk][s] = dot(q[b,hk,s,:], k[b,hk,s,:])  (fp32 from f16)
// block 256 = 16 s x 16 dkg; grid = B*HK*S/16 = 4096
// ------------------------------------------------------------------
__global__ __launch_bounds__(256) void qk_kernel(const f16* __restrict__ qh,
                                                 const f16* __restrict__ kh,
                                                 float* __restrict__ qk) {
    int blk = blockIdx.x;
    int bh = blk >> 7;            // b*16+hk
    int s0 = (blk & 127) * 16;
    int tid = threadIdx.x;
    int sl = tid >> 4, dkg = tid & 15;
    long base = ((long)bh * 2048 + s0 + sl) * 128 + dkg * 8;
    f16x8 kv = *(const f16x8*)(kh + base);
    f16x8 qv = *(const f16x8*)(qh + base);
    float d = 0.f;
#pragma unroll
    for (int i = 0; i < 8; ++i) d = fmaf((float)qv[i], (float)kv[i], d);
    d = rowsum16(d);
    if (dkg == 0) qk[(long)bh * 2048 + s0 + sl] = d;
}

// ------------------------------------------------------------------
// sequential gated delta scan, chunked LDS staging.
// f32 LDS in SPLIT halves (16B/lane stride -> no bank conflicts).
// step (A3=q.k precomputed):
//   S *= e; A1=k.S, A2=q.S -> rowsum x2 ->
//   dv = b(v - A1); po = A2 + qk*dv; S += k*dv.
// block: 512 threads = 32 cols x 16 dkg; grid 256 = (b, hv, vs in [0,4))
// ------------------------------------------------------------------
#define CH 32  // steps per staged chunk

struct StepRegs {
    f32x4 kA, kB, qA, qB;
    float v, e, b, qk;
};

__global__ __launch_bounds__(512) void scan_kernel(const f16* __restrict__ qh,
                                                   const f16* __restrict__ kh,
                                                   const f16* __restrict__ vh,
                                                   const float* __restrict__ eg,
                                                   const float* __restrict__ bt,
                                                   const float* __restrict__ qkb,
                                                   f16* __restrict__ o) {
    __shared__ float Lk0[CH * 64];
    __shared__ float Lk1[CH * 64];
    __shared__ float Lq0[CH * 64];
    __shared__ float Lq1[CH * 64];
    __shared__ float Lv[CH * 32];
    __shared__ f32x4 Lc[CH];

    int bid = blockIdx.x;
    int vs = bid & 3;
    int hv = (bid >> 2) & 31;
    int b = bid >> 7;
    int tid = threadIdx.x;
    int col = tid >> 4, dkg = tid & 15;
    int vcol = vs * 32 + col;
    const f16* kp = kh + ((long)b * 16 + (hv >> 1)) * 2048 * 128;
    const f16* qp = qh + ((long)b * 16 + (hv >> 1)) * 2048 * 128;
    const f16* vp = vh + ((long)b * 32 + hv) * 2048 * 128;
    const float* egp = eg + ((long)b * 32 + hv) * 2048;
    const float* btp = bt + ((long)b * 32 + hv) * 2048;
    const float* qkp = qkb + ((long)b * 16 + (hv >> 1)) * 2048;
    f16* op = o + ((long)b * 2048 * 32 + hv) * 128 + vcol;

    // staging registers
    f16x8 rk, rq, rv;
    float re = 0.f, rb = 0.f, rqk = 0.f;
    const int vstep = tid >> 2, vpart = tid & 3;  // v staging (tid<128)

    auto issue_loads = [&](int c) {
        long base = (long)c * CH * 128;
        rk = *(const f16x8*)(kp + base + tid * 8);
        rq = *(const f16x8*)(qp + base + tid * 8);
        if (tid < 128) rv = *(const f16x8*)(vp + base + vstep * 128 + vs * 32 + vpart * 8);
        if (tid < CH) { re = egp[c * CH + tid]; rb = btp[c * CH + tid]; rqk = qkp[c * CH + tid]; }
    };
    auto commit = [&]() {
        f32x4 lo, hi;
#pragma unroll
        for (int i = 0; i < 4; ++i) { lo[i] = (float)rk[i]; hi[i] = (float)rk[4 + i]; }
        ((f32x4*)Lk0)[tid] = lo;  // byte-linear: tid*16
        ((f32x4*)Lk1)[tid] = hi;
#pragma unroll
        for (int i = 0; i < 4; ++i) { lo[i] = (float)rq[i]; hi[i] = (float)rq[4 + i]; }
        ((f32x4*)Lq0)[tid] = lo;
        ((f32x4*)Lq1)[tid] = hi;
        if (tid < 128) {
#pragma unroll
            for (int i = 0; i < 4; ++i) { lo[i] = (float)rv[i]; hi[i] = (float)rv[4 + i]; }
            ((f32x4*)Lv)[tid * 2] = lo;
            ((f32x4*)Lv)[tid * 2 + 1] = hi;
        }
        if (tid < CH) { f32x4 cc = {re, rb, rqk, 0.f}; Lc[tid] = cc; }
    };

    float St[8] = {0.f, 0.f, 0.f, 0.f, 0.f, 0.f, 0.f, 0.f};

    auto lds_ld = [&](int s, StepRegs& r) {
        r.kA = ((const f32x4*)Lk0)[s * 16 + dkg];
        r.kB = ((const f32x4*)Lk1)[s * 16 + dkg];
        r.qA = ((const f32x4*)Lq0)[s * 16 + dkg];
        r.qB = ((const f32x4*)Lq1)[s * 16 + dkg];
        r.v = Lv[s * 32 + col];
        f32x4 cc = Lc[s];
        r.e = cc[0]; r.b = cc[1]; r.qk = cc[2];
    };
    auto do_step = [&](const StepRegs& L, int s) {
        float kf[8] = {L.kA[0], L.kA[1], L.kA[2], L.kA[3], L.kB[0], L.kB[1], L.kB[2], L.kB[3]};
        float qf[8] = {L.qA[0], L.qA[1], L.qA[2], L.qA[3], L.qB[0], L.qB[1], L.qB[2], L.qB[3]};
        float e = L.e;
#pragma unroll
        for (int i = 0; i < 8; ++i) St[i] *= e;
        float A1 = 0.f, A2 = 0.f;
#pragma unroll
        for (int i = 0; i < 8; ++i) {
            A1 = fmaf(kf[i], St[i], A1);
            A2 = fmaf(qf[i], St[i], A2);
        }
        rowsum16x2(A1, A2);
        float dv = L.b * (L.v - A1);
        float po = fmaf(L.qk, dv, A2);
#pragma unroll
        for (int i = 0; i < 8; ++i) St[i] = fmaf(kf[i], dv, St[i]);
        if (dkg == 0) op[(long)s * 4096] = (f16)po;
    };

    // prologue: stage chunk 0
    issue_loads(0);
    commit();
    __syncthreads();

    for (int c = 0; c < 2048 / CH; ++c) {
        if (c + 1 < 2048 / CH) issue_loads(c + 1);  // in flight during compute
        StepRegs A, Bv;
        lds_ld(0, A);
        for (int s = 0; s < CH; s += 2) {
            lds_ld(s + 1, Bv);
            do_step(A, c * CH + s);
            if (s + 2 < CH) lds_ld(s + 2, A);
            do_step(Bv, c * CH + s + 1);
        }
        __syncthreads();  // all waves done reading LDS
        if (c + 1 < 2048 / CH) commit();
        __syncthreads();
    }
}

// ------------------------------------------------------------------
// y = rmsnorm(o * silu(z)) * norm_w  -> f16   (o is f16 now)
// ------------------------------------------------------------------
__global__ __launch_bounds__(256) void gate_kernel(const f16* __restrict__ o,
                                                   const f16* __restrict__ qkvz,
                                                   const float* __restrict__ norm_w,
                                                   f16* __restrict__ y) {
    int token = blockIdx.x;  // b*2048 + s
    int tid = threadIdx.x;
    int hv = tid >> 3, part = tid & 7;
    int dv0 = part * 16;
    const f16* orow = o + ((long)token * 32 + hv) * 128 + dv0;
    long zcol = (long)(hv >> 1) * 768 + 512 + (hv & 1) * 128 + dv0;
    const f16* zrow = qkvz + (long)token * 12288 + zcol;
    float yv[16];
    float ss = 0.f;
#pragma unroll
    for (int i = 0; i < 16; ++i) {
        float ov = (float)orow[i];
        float zv = (float)zrow[i];
        float gt = zv / (1.f + expf(-zv));
        float v = ov * gt;
        yv[i] = v;
        ss += v * v;
    }
    ss += __shfl_xor(ss, 1); ss += __shfl_xor(ss, 2); ss += __shfl_xor(ss, 4);
    float scale = rsqrtf(ss * (1.f / 128.f) + 1e-6f);
    f16* yrow = y + (long)token * 4096 + hv * 128 + dv0;
#pragma unroll
    for (int i = 0; i < 16; ++i) yrow[i] = (f16)(yv[i] * scale * norm_w[dv0 + i]);
}

// ------------------------------------------------------------------
// Workspace (242 MB, time-aliased):
//   [0,96)        qkvz16           (gemm1 -> gate)
//   [96,112)      x16              (prep -> gemm1)
//   [112,160)     WT               (prep -> gemm1)
//   [96,128)      ob f16           (scan -> gate)   — over dead x16+WT
//   [128,128.25)  qkb f32          (qk -> scan)     — over dead WT
//   [160,176)     WTo              (prep -> gemm2)
//   [176,240)     qh/kh/vh         (conv -> scan); [176,208) reused as y16
//   [240,242)     bab/egb/btb
// ------------------------------------------------------------------
extern "C" void kernel_launch(void* const* d_in, const int* in_sizes, int n_in,
                              void* d_out, int out_size, void* d_ws, size_t ws_size,
                              hipStream_t stream) {
    const float* x       = (const float*)d_in[0];
    const float* w_qkvz  = (const float*)d_in[1];
    const float* w_ba    = (const float*)d_in[2];
    const float* conv_w  = (const float*)d_in[3];
    const float* conv_b  = (const float*)d_in[4];
    const float* a_log   = (const float*)d_in[5];
    const float* dt_bias = (const float*)d_in[6];
    const float* norm_w  = (const float*)d_in[7];
    const float* w_o     = (const float*)d_in[8];
    float* out = (float*)d_out;

    char* ws = (char*)d_ws;
    const size_t MB = 1024 * 1024;
    f16*   qkvz16 = (f16*)ws;                      // 96 MB
    f16*   x16    = (f16*)(ws + 96 * MB);          // 16 MB
    f16*   WT     = (f16*)(ws + 112 * MB);         // 48 MB
    f16*   ob     = (f16*)(ws + 96 * MB);          // 32 MB (after gemm1)
    float* qkb    = (float*)(ws + 128 * MB);       // 256 KB (after gemm1)
    f16*   WTo    = (f16*)(ws + 160 * MB);         // 16 MB
    f16*   qh     = (f16*)(ws + 176 * MB);         // 16 MB
    f16*   kh     = (f16*)(ws + 192 * MB);         // 16 MB
    f16*   vh     = (f16*)(ws + 208 * MB);         // 32 MB
    f16*   y16    = (f16*)(ws + 176 * MB);         // 32 MB (after scan)
    float* bab    = (float*)(ws + 240 * MB);       // 1 MB
    float* egb    = (float*)(ws + 241 * MB);       // 0.5 MB
    float* btb    = (float*)(ws + 241 * MB + 512 * 1024);  // 0.5 MB

    // prep
    cvt16_kernel<<<8192, 256, 0, stream>>>(x, x16, 4096 * 2048 / 4);
    transpose16_kernel<<<dim3(12288 / 64, 2048 / 64), 256, 0, stream>>>(w_qkvz, WT, 2048, 12288);
    transpose16_kernel<<<dim3(2048 / 64, 4096 / 64), 256, 0, stream>>>(w_o, WTo, 4096, 2048);

    // qkvz = x @ w_qkvz
    gemm16_kernel<1><<<dim3(12288 / 128, 4096 / 128), 256, 0, stream>>>(x16, WT, qkvz16, 4096, 12288, 2048);
    // ba = x @ w_ba
    ba_gemm_kernel<<<256, 256, 0, stream>>>(x, w_ba, bab);

    // conv + silu + l2norm
    conv_kernel<<<dim3(64, 64, 2), 256, 0, stream>>>(qkvz16, conv_w, conv_b, qh, kh, vh);
    // gate scalars
    gb_kernel<<<512, 256, 0, stream>>>(bab, a_log, dt_bias, egb, btb);
    // qk dots (hoisted out of scan)
    qk_kernel<<<4096, 256, 0, stream>>>(qh, kh, qkb);

    // sequential delta-rule scan
    scan_kernel<<<256, 512, 0, stream>>>(qh, kh, vh, egb, btb, qkb, ob);

    // gating + rmsnorm -> y16
    gate_kernel<<<4096, 256, 0, stream>>>(ob, qkvz16, norm_w, y16);

    // out = y @ w_o
    gemm16_kernel<0><<<dim3(2048 / 128, 4096 / 128), 256, 0, stream>>>(y16, WTo, out, 4096, 2048, 4096);
}

// Round 7
// 1156.408 us; speedup vs baseline: 1.0998x; 1.0051x over previous
//
#include <hip/hip_runtime.h>

typedef _Float16 f16;
typedef _Float16 f16x2 __attribute__((ext_vector_type(2)));
typedef _Float16 f16x4 __attribute__((ext_vector_type(4)));
typedef _Float16 f16x8 __attribute__((ext_vector_type(8)));
typedef float f32x4 __attribute__((ext_vector_type(4)));

#define QSCALE 0.08838834764831845f  // DK^-0.5

// ------------------------------------------------------------------
// convert fp32 -> f16 (vectorized x4)
// ------------------------------------------------------------------
__global__ __launch_bounds__(256) void cvt16_kernel(const float* __restrict__ in,
                                                    f16* __restrict__ out, int n4) {
    int i = blockIdx.x * 256 + threadIdx.x;
    if (i >= n4) return;
    f32x4 v = ((const f32x4*)in)[i];
    f16x4 h;
    h[0] = (f16)v[0]; h[1] = (f16)v[1]; h[2] = (f16)v[2]; h[3] = (f16)v[3];
    ((f16x4*)out)[i] = h;
}

// ------------------------------------------------------------------
// transpose fp32 [R][C] -> f16 [C][R]
// ------------------------------------------------------------------
__global__ __launch_bounds__(256) void transpose16_kernel(const float* __restrict__ in,
                                                          f16* __restrict__ out, int R, int C) {
    __shared__ f16 tile[64][66];
    int c0 = blockIdx.x * 64, r0 = blockIdx.y * 64;
    int tid = threadIdx.x;
#pragma unroll
    for (int i = 0; i < 16; ++i) {
        int idx = i * 256 + tid;
        int r = idx >> 6, c = idx & 63;
        tile[r][c] = (f16)in[(long)(r0 + r) * C + (c0 + c)];
    }
    __syncthreads();
#pragma unroll
    for (int i = 0; i < 16; ++i) {
        int idx = i * 256 + tid;
        int orow = idx >> 6, oc = idx & 63;
        out[(long)(c0 + orow) * R + (r0 + oc)] = tile[oc][orow];
    }
}

// ------------------------------------------------------------------
// f16 MFMA GEMM: C[m][n] = sum_k A[m][k] * Bt[n][k]
// 128x128 tile, BK=64, 4 waves (2x2), XOR-swizzled LDS, reg-staged.
// ------------------------------------------------------------------
template <int F16OUT>
__global__ __launch_bounds__(256) void gemm16_kernel(const f16* __restrict__ A,
                                                     const f16* __restrict__ Bt,
                                                     void* __restrict__ Cout,
                                                     int M, int N, int Kd) {
    __shared__ f16 sA[128 * 64];
    __shared__ f16 sB[128 * 64];
    const int tid = threadIdx.x;
    const int lane = tid & 63, wv = tid >> 6;
    const int wm = wv >> 1, wn = wv & 1;
    const int m0 = blockIdx.y * 128, n0 = blockIdx.x * 128;
    const int lrow = lane & 15, lk = lane >> 4;
    f32x4 acc[4][4] = {};
    for (int k0 = 0; k0 < Kd; k0 += 64) {
        __syncthreads();
#pragma unroll
        for (int j = 0; j < 4; ++j) {
            int P = (tid + j * 256) * 16;
            int row = P >> 7;
            int sw = P ^ ((row & 7) << 4);
            int koff = P & 127;
            const char* ga = (const char*)(A + (long)(m0 + row) * Kd + k0) + koff;
            *(f32x4*)((char*)sA + sw) = *(const f32x4*)ga;
            const char* gb = (const char*)(Bt + (long)(n0 + row) * Kd + k0) + koff;
            *(f32x4*)((char*)sB + sw) = *(const f32x4*)gb;
        }
        __syncthreads();
#pragma unroll
        for (int kk = 0; kk < 2; ++kk) {
            f16x8 af[4], bf[4];
#pragma unroll
            for (int i = 0; i < 4; ++i) {
                int arow = wm * 64 + i * 16 + lrow;
                int abyte = arow * 128 + kk * 64 + lk * 16;
                af[i] = *(const f16x8*)((const char*)sA + (abyte ^ ((arow & 7) << 4)));
                int brow = wn * 64 + i * 16 + lrow;
                int bbyte = brow * 128 + kk * 64 + lk * 16;
                bf[i] = *(const f16x8*)((const char*)sB + (bbyte ^ ((brow & 7) << 4)));
            }
#pragma unroll
            for (int i = 0; i < 4; ++i)
#pragma unroll
                for (int j = 0; j < 4; ++j)
                    acc[i][j] = __builtin_amdgcn_mfma_f32_16x16x32_f16(af[i], bf[j], acc[i][j], 0, 0, 0);
        }
    }
#pragma unroll
    for (int i = 0; i < 4; ++i) {
        int gm_base = m0 + wm * 64 + i * 16 + lk * 4;
#pragma unroll
        for (int j = 0; j < 4; ++j) {
            int gn = n0 + wn * 64 + j * 16 + lrow;
#pragma unroll
            for (int r = 0; r < 4; ++r) {
                long idx = (long)(gm_base + r) * N + gn;
                if (F16OUT) ((f16*)Cout)[idx] = (f16)acc[i][j][r];
                else        ((float*)Cout)[idx] = acc[i][j][r];
            }
        }
    }
}

// ------------------------------------------------------------------
// ba = x @ w_ba   (fp32)
// ------------------------------------------------------------------
__global__ __launch_bounds__(256) void ba_gemm_kernel(const float* __restrict__ x,
                                                      const float* __restrict__ w,
                                                      float* __restrict__ ba) {
    __shared__ float xs[16][256];
    int tid = threadIdx.x;
    int t0 = blockIdx.x * 16;
    int o = tid & 63, tg = tid >> 6;
    float acc[4] = {0.f, 0.f, 0.f, 0.f};
    for (int kc = 0; kc < 2048; kc += 256) {
        __syncthreads();
#pragma unroll
        for (int i = 0; i < 16; ++i) {
            int idx = i * 256 + tid;
            int tok = idx >> 8, k = idx & 255;
            xs[tok][k] = x[(long)(t0 + tok) * 2048 + kc + k];
        }
        __syncthreads();
        for (int k = 0; k < 256; ++k) {
            float wv = w[(long)(kc + k) * 64 + o];
#pragma unroll
            for (int j = 0; j < 4; ++j) acc[j] += xs[tg * 4 + j][k] * wv;
        }
    }
#pragma unroll
    for (int j = 0; j < 4; ++j) ba[(long)(t0 + tg * 4 + j) * 64 + o] = acc[j];
}

// ------------------------------------------------------------------
// depthwise causal conv(K=4) + bias + SiLU (+ L2norm for q/k heads)
// ------------------------------------------------------------------
__global__ __launch_bounds__(256) void conv_kernel(const f16* __restrict__ qkvz,
                                                   const float* __restrict__ cw,
                                                   const float* __restrict__ cb,
                                                   f16* __restrict__ qh,
                                                   f16* __restrict__ kh,
                                                   f16* __restrict__ vh) {
    __shared__ float Lin[35 * 128];
    __shared__ float Lout[32 * 128];
    __shared__ float Lsc[32];
    int g = blockIdx.x;
    int s0 = blockIdx.y * 32;
    int b = blockIdx.z;
    int tid = threadIdx.x;
    int colbase, chbase;
    f16* outp;
    bool donorm;
    float nmul;
    if (g < 16) {
        colbase = g * 768; chbase = g * 128;
        outp = qh + (((long)b * 16 + g) * 2048 + s0) * 128;
        donorm = true; nmul = QSCALE;
    } else if (g < 32) {
        int hk = g - 16;
        colbase = hk * 768 + 128; chbase = 2048 + hk * 128;
        outp = kh + (((long)b * 16 + hk) * 2048 + s0) * 128;
        donorm = true; nmul = 1.f;
    } else {
        int hv = g - 32;
        colbase = (hv >> 1) * 768 + 256 + (hv & 1) * 128; chbase = 4096 + hv * 128;
        outp = vh + (((long)b * 32 + hv) * 2048 + s0) * 128;
        donorm = false; nmul = 1.f;
    }
    for (int idx = tid; idx < 35 * 128; idx += 256) {
        int sr = idx >> 7, c = idx & 127;
        int s = s0 + sr - 3;
        Lin[idx] = (s >= 0) ? (float)qkvz[((long)b * 2048 + s) * 12288 + colbase + c] : 0.f;
    }
    __syncthreads();
    int c = tid & 127, sg = tid >> 7;
    float w0 = cw[(chbase + c) * 4 + 0];
    float w1 = cw[(chbase + c) * 4 + 1];
    float w2 = cw[(chbase + c) * 4 + 2];
    float w3 = cw[(chbase + c) * 4 + 3];
    float bias = cb[chbase + c];
#pragma unroll
    for (int j = 0; j < 16; ++j) {
        int sl = sg * 16 + j;
        float v = w0 * Lin[sl * 128 + c] + w1 * Lin[(sl + 1) * 128 + c] +
                  w2 * Lin[(sl + 2) * 128 + c] + w3 * Lin[(sl + 3) * 128 + c] + bias;
        v = v / (1.f + expf(-v));  // SiLU
        Lout[sl * 128 + c] = v;
    }
    __syncthreads();
    if (donorm) {
        int token = tid >> 3, part = tid & 7;
        float ss = 0.f;
#pragma unroll
        for (int i = 0; i < 16; ++i) {
            float v = Lout[token * 128 + part * 16 + i];
            ss += v * v;
        }
        ss += __shfl_xor(ss, 1); ss += __shfl_xor(ss, 2); ss += __shfl_xor(ss, 4);
        if (part == 0) Lsc[token] = rsqrtf(ss + 1e-6f) * nmul;
        __syncthreads();
#pragma unroll
        for (int j = 0; j < 16; ++j) {
            int sl = sg * 16 + j;
            outp[(long)sl * 128 + c] = (f16)(Lout[sl * 128 + c] * Lsc[sl]);
        }
    } else {
#pragma unroll
        for (int j = 0; j < 16; ++j) {
            int sl = sg * 16 + j;
            outp[(long)sl * 128 + c] = (f16)Lout[sl * 128 + c];
        }
    }
}

// ------------------------------------------------------------------
// eg = exp(g), beta = sigmoid(b)
// ------------------------------------------------------------------
__global__ __launch_bounds__(256) void gb_kernel(const float* __restrict__ ba,
                                                 const float* __restrict__ a_log,
                                                 const float* __restrict__ dt_bias,
                                                 float* __restrict__ eg,
                                                 float* __restrict__ bt) {
    int idx = blockIdx.x * 256 + threadIdx.x;  // ((b*32+hv)*2048 + s)
    if (idx >= 2 * 32 * 2048) return;
    int s = idx & 2047;
    int hv = (idx >> 11) & 31;
    int b = idx >> 16;
    int gg = hv & 1, hk = hv >> 1;
    long base = ((long)b * 2048 + s) * 64 + hk * 4;
    float bv = ba[base + gg];
    float av = ba[base + 2 + gg];
    float xx = av + dt_bias[hv];
    float sp = (xx > 20.f) ? xx : log1pf(expf(xx));
    float gv = -expf(a_log[hv]) * sp;
    eg[idx] = expf(gv);
    bt[idx] = 1.f / (1.f + expf(-bv));
}

// ------------------------------------------------------------------
// 16-lane DPP row sums (constant-ctrl templated; interleaved x4 for ILP)
// ------------------------------------------------------------------
__device__ __forceinline__ float rowsum16(float x) {
    int v;
    v = __float_as_int(x);
    x += __int_as_float(__builtin_amdgcn_update_dpp(v, v, 0x121, 0xF, 0xF, false));
    v = __float_as_int(x);
    x += __int_as_float(__builtin_amdgcn_update_dpp(v, v, 0x122, 0xF, 0xF, false));
    v = __float_as_int(x);
    x += __int_as_float(__builtin_amdgcn_update_dpp(v, v, 0x124, 0xF, 0xF, false));
    v = __float_as_int(x);
    x += __int_as_float(__builtin_amdgcn_update_dpp(v, v, 0x128, 0xF, 0xF, false));
    return x;
}
template <int CTRL>
__device__ __forceinline__ void dpp_add4(float& a, float& b, float& c, float& d) {
    int va = __float_as_int(a), vb = __float_as_int(b), vc = __float_as_int(c), vd = __float_as_int(d);
    a += __int_as_float(__builtin_amdgcn_update_dpp(va, va, CTRL, 0xF, 0xF, false));
    b += __int_as_float(__builtin_amdgcn_update_dpp(vb, vb, CTRL, 0xF, 0xF, false));
    c += __int_as_float(__builtin_amdgcn_update_dpp(vc, vc, CTRL, 0xF, 0xF, false));
    d += __int_as_float(__builtin_amdgcn_update_dpp(vd, vd, CTRL, 0xF, 0xF, false));
}
__device__ __forceinline__ void rowsum16x4(float& a, float& b, float& c, float& d) {
    dpp_add4<0x121>(a, b, c, d);
    dpp_add4<0x122>(a, b, c, d);
    dpp_add4<0x124>(a, b, c, d);
    dpp_add4<0x128>(a, b, c, d);
}

// ------------------------------------------------------------------
// cross_kernel: per (b,hv,grp of 4 steps) precompute coeffs:
//  o0: P_i (cumprod of e in group)
//  o1..o4: KK_ij=(P_i/P_j)(k_i.k_j) (j<i), QK_ij=(P_i/P_j)(q_i.k_j) (j<=i)
//  o5: beta_i; o6: R_j = P3/P_j (j=0,1,2)
// block 256 = 16 slots x 16 dkg; 4 groups per block; grid = 2*32*128
// ------------------------------------------------------------------
__global__ __launch_bounds__(256) void cross_kernel(const f16* __restrict__ qh,
                                                    const f16* __restrict__ kh,
                                                    const float* __restrict__ eg,
                                                    const float* __restrict__ bt,
                                                    float* __restrict__ scal) {
    __shared__ float dots[16];
    int bid = blockIdx.x;
    int grp0 = (bid & 127) * 4;
    int hv = (bid >> 7) & 31;
    int b = bid >> 12;
    int bh = b * 16 + (hv >> 1);
    int tid = threadIdx.x;
    int slot = tid >> 4, dkg = tid & 15;
    // nibble tables: i and j per slot (slots 0..5 kk, 6..15 qk)
    const unsigned long long AI = 0x3333222110333221ull;
    const unsigned long long BJ = 0x3210210100210100ull;
    int ii = (int)((AI >> (slot * 4)) & 15);
    int jj = (int)((BJ >> (slot * 4)) & 15);
    const f16* abase = (slot < 6) ? kh : qh;
    const float* egp = eg + ((long)b * 32 + hv) * 2048;
    const float* btp = bt + ((long)b * 32 + hv) * 2048;

    for (int gl = 0; gl < 4; ++gl) {
        int grp = grp0 + gl;
        int t0 = grp * 4;
        f16x8 av = *(const f16x8*)(abase + ((long)bh * 2048 + t0 + ii) * 128 + dkg * 8);
        f16x8 bv = *(const f16x8*)(kh + ((long)bh * 2048 + t0 + jj) * 128 + dkg * 8);
        float d = 0.f;
#pragma unroll
        for (int e = 0; e < 8; ++e) d = fmaf((float)av[e], (float)bv[e], d);
        d = rowsum16(d);
        if (dkg == 0) dots[slot] = d;
        __syncthreads();
        if (tid == 0) {
            float e0 = egp[t0], e1 = egp[t0 + 1], e2 = egp[t0 + 2], e3 = egp[t0 + 3];
            float P0 = e0, P1 = P0 * e1, P2 = P1 * e2, P3 = P2 * e3;
            float r10 = e1, r21 = e2, r32 = e3;
            float r20 = e1 * e2, r31 = e2 * e3;
            float r30 = r20 * e3;
            float* outp = scal + ((long)(b * 32 + hv) * 512 + grp) * 32;
            f32x4 o0 = {P0, P1, P2, P3};
            f32x4 o1 = {r10 * dots[0], r20 * dots[1], r21 * dots[2], r30 * dots[3]};
            f32x4 o2 = {r31 * dots[4], r32 * dots[5], dots[6], r10 * dots[7]};
            f32x4 o3 = {dots[8], r20 * dots[9], r21 * dots[10], dots[11]};
            f32x4 o4 = {r30 * dots[12], r31 * dots[13], r32 * dots[14], dots[15]};
            f32x4 o5 = {btp[t0], btp[t0 + 1], btp[t0 + 2], btp[t0 + 3]};
            f32x4 o6 = {r30, r31, r32, 0.f};  // R_j = P3/P_j
            ((f32x4*)outp)[0] = o0; ((f32x4*)outp)[1] = o1; ((f32x4*)outp)[2] = o2;
            ((f32x4*)outp)[3] = o3; ((f32x4*)outp)[4] = o4; ((f32x4*)outp)[5] = o5;
            ((f32x4*)outp)[6] = o6;
        }
        __syncthreads();
    }
}

// ------------------------------------------------------------------
// gated delta scan, 4-step blocked, f16 LDS, 2 dv-cols per thread.
// block 256 = 16 dkg x 16 colq; grid 256 = (b, hv, vs in [0,4))
// ------------------------------------------------------------------
#define CH 32
#define NG 8  // groups of 4 per chunk

__global__ __launch_bounds__(256, 1) void scan_kernel(const f16* __restrict__ qh,
                                                      const f16* __restrict__ kh,
                                                      const f16* __restrict__ vh,
                                                      const float* __restrict__ scal,
                                                      f16* __restrict__ o) {
    __shared__ f16 Lk[CH * 128];
    __shared__ f16 Lq[CH * 128];
    __shared__ f16 Lv[CH * 32];

    int bid = blockIdx.x;
    int vs = bid & 3;
    int hv = (bid >> 2) & 31;
    int b = bid >> 7;
    int tid = threadIdx.x;
    int dkg = tid & 15, colq = tid >> 4;
    int c0 = vs * 32 + colq * 2;
    const f16* kp = kh + ((long)b * 16 + (hv >> 1)) * 2048 * 128;
    const f16* qp = qh + ((long)b * 16 + (hv >> 1)) * 2048 * 128;
    const f16* vp = vh + ((long)b * 32 + hv) * 2048 * 128;
    const float* scp = scal + ((long)(b * 32 + hv) * 512) * 32;
    f16* op = o + ((long)b * 2048 * 32 + hv) * 128 + c0;

    f16x8 rk0, rk1, rq0, rq1;
    f16x4 rv;
    auto issue_loads = [&](int c) {
        long base = (long)c * CH * 128;
        rk0 = *(const f16x8*)(kp + base + tid * 8);
        rk1 = *(const f16x8*)(kp + base + 2048 + tid * 8);
        rq0 = *(const f16x8*)(qp + base + tid * 8);
        rq1 = *(const f16x8*)(qp + base + 2048 + tid * 8);
        rv = *(const f16x4*)(vp + base + (tid >> 3) * 128 + vs * 32 + (tid & 7) * 4);
    };
    auto commit = [&]() {
        *(f16x8*)(Lk + tid * 8) = rk0;
        *(f16x8*)(Lk + 2048 + tid * 8) = rk1;
        *(f16x8*)(Lq + tid * 8) = rq0;
        *(f16x8*)(Lq + 2048 + tid * 8) = rq1;
        *(f16x4*)(Lv + tid * 4) = rv;
    };

    float St0[8] = {0.f, 0.f, 0.f, 0.f, 0.f, 0.f, 0.f, 0.f};
    float St1[8] = {0.f, 0.f, 0.f, 0.f, 0.f, 0.f, 0.f, 0.f};

    issue_loads(0);
    commit();
    __syncthreads();

    // scalar coeffs for group 0
    f32x4 s0, s1, s2, s3, s4, s5, s6;
    {
        const f32x4* sq = (const f32x4*)scp;
        s0 = sq[0]; s1 = sq[1]; s2 = sq[2]; s3 = sq[3]; s4 = sq[4]; s5 = sq[5]; s6 = sq[6];
    }

    for (int c = 0; c < 2048 / CH; ++c) {
        if (c + 1 < 2048 / CH) issue_loads(c + 1);
        for (int g = 0; g < NG; ++g) {
            int gg = c * NG + g;
            // prefetch next group's coeffs
            int ng = (gg + 1 < 512) ? gg + 1 : gg;
            const f32x4* nq = (const f32x4*)(scp + (long)ng * 32);
            f32x4 t0v = nq[0], t1v = nq[1], t2v = nq[2], t3v = nq[3], t4v = nq[4], t5v = nq[5], t6v = nq[6];

            int sb = g * 4;
            f16x8 hk[4], hq[4];
            f16x2 vv[4];
#pragma unroll
            for (int i = 0; i < 4; ++i) {
                hk[i] = *(const f16x8*)(Lk + (sb + i) * 128 + dkg * 8);
                hq[i] = *(const f16x8*)(Lq + (sb + i) * 128 + dkg * 8);
                vv[i] = *(const f16x2*)(Lv + (sb + i) * 32 + colq * 2);
            }
            float kf[4][8];
#pragma unroll
            for (int i = 0; i < 4; ++i)
#pragma unroll
                for (int e = 0; e < 8; ++e) kf[i][e] = (float)hk[i][e];

            float a0[4], a1[4], c0v[4], c1v[4];
#pragma unroll
            for (int i = 0; i < 4; ++i) {
                float qf[8];
#pragma unroll
                for (int e = 0; e < 8; ++e) qf[e] = (float)hq[i][e];
                float sa0 = 0.f, sa1 = 0.f, sc0 = 0.f, sc1 = 0.f;
#pragma unroll
                for (int e = 0; e < 8; ++e) {
                    sa0 = fmaf(kf[i][e], St0[e], sa0);
                    sa1 = fmaf(kf[i][e], St1[e], sa1);
                    sc0 = fmaf(qf[e], St0[e], sc0);
                    sc1 = fmaf(qf[e], St1[e], sc1);
                }
                a0[i] = sa0; a1[i] = sa1; c0v[i] = sc0; c1v[i] = sc1;
            }
            rowsum16x4(a0[0], a0[1], a0[2], a0[3]);
            rowsum16x4(a1[0], a1[1], a1[2], a1[3]);
            rowsum16x4(c0v[0], c0v[1], c0v[2], c0v[3]);
            rowsum16x4(c1v[0], c1v[1], c1v[2], c1v[3]);

            float P0 = s0[0], P1 = s0[1], P2 = s0[2], P3 = s0[3];
            float KK10 = s1[0], KK20 = s1[1], KK21 = s1[2], KK30 = s1[3];
            float KK31 = s2[0], KK32 = s2[1], QK00 = s2[2], QK10 = s2[3];
            float QK11 = s3[0], QK20 = s3[1], QK21 = s3[2], QK22 = s3[3];
            float QK30 = s4[0], QK31 = s4[1], QK32 = s4[2], QK33 = s4[3];
            float B0 = s5[0], B1 = s5[1], B2 = s5[2], B3 = s5[3];
            float R0 = s6[0], R1 = s6[1], R2 = s6[2];

            // col 0 tail
            float x0 = (float)vv[0][0], x1 = (float)vv[1][0], x2 = (float)vv[2][0], x3 = (float)vv[3][0];
            float d00 = B0 * (x0 - P0 * a0[0]);
            float d01 = B1 * (x1 - P1 * a0[1] - KK10 * d00);
            float d02 = B2 * (x2 - P2 * a0[2] - KK20 * d00 - KK21 * d01);
            float d03 = B3 * (x3 - P3 * a0[3] - KK30 * d00 - KK31 * d01 - KK32 * d02);
            float o00 = fmaf(QK00, d00, P0 * c0v[0]);
            float o01 = P1 * c0v[1] + QK10 * d00 + QK11 * d01;
            float o02 = P2 * c0v[2] + QK20 * d00 + QK21 * d01 + QK22 * d02;
            float o03 = P3 * c0v[3] + QK30 * d00 + QK31 * d01 + QK32 * d02 + QK33 * d03;
            // col 1 tail
            float y0 = (float)vv[0][1], y1 = (float)vv[1][1], y2 = (float)vv[2][1], y3 = (float)vv[3][1];
            float d10 = B0 * (y0 - P0 * a1[0]);
            float d11 = B1 * (y1 - P1 * a1[1] - KK10 * d10);
            float d12 = B2 * (y2 - P2 * a1[2] - KK20 * d10 - KK21 * d11);
            float d13 = B3 * (y3 - P3 * a1[3] - KK30 * d10 - KK31 * d11 - KK32 * d12);
            float o10 = fmaf(QK00, d10, P0 * c1v[0]);
            float o11 = P1 * c1v[1] + QK10 * d10 + QK11 * d11;
            float o12 = P2 * c1v[2] + QK20 * d10 + QK21 * d11 + QK22 * d12;
            float o13 = P3 * c1v[3] + QK30 * d10 + QK31 * d11 + QK32 * d12 + QK33 * d13;

            // state update: S = P3*S + sum_j (R_j*d_j) k_j
            float w00 = R0 * d00, w01 = R1 * d01, w02 = R2 * d02, w03 = d03;
            float w10 = R0 * d10, w11 = R1 * d11, w12 = R2 * d12, w13 = d13;
#pragma unroll
            for (int e = 0; e < 8; ++e) {
                St0[e] = fmaf(P3, St0[e],
                          fmaf(w00, kf[0][e], fmaf(w01, kf[1][e], fmaf(w02, kf[2][e], w03 * kf[3][e]))));
                St1[e] = fmaf(P3, St1[e],
                          fmaf(w10, kf[0][e], fmaf(w11, kf[1][e], fmaf(w12, kf[2][e], w13 * kf[3][e]))));
            }

            if (dkg == 0) {
                long tb = (long)(c * CH + sb) * 4096;
                f16x2 z0; z0[0] = (f16)o00; z0[1] = (f16)o10; *(f16x2*)(op + tb) = z0;
                f16x2 z1; z1[0] = (f16)o01; z1[1] = (f16)o11; *(f16x2*)(op + tb + 4096) = z1;
                f16x2 z2; z2[0] = (f16)o02; z2[1] = (f16)o12; *(f16x2*)(op + tb + 8192) = z2;
                f16x2 z3; z3[0] = (f16)o03; z3[1] = (f16)o13; *(f16x2*)(op + tb + 12288) = z3;
            }
            s0 = t0v; s1 = t1v; s2 = t2v; s3 = t3v; s4 = t4v; s5 = t5v; s6 = t6v;
        }
        __syncthreads();
        if (c + 1 < 2048 / CH) commit();
        __syncthreads();
    }
}

// ------------------------------------------------------------------
// y = rmsnorm(o * silu(z)) * norm_w  -> f16
// ------------------------------------------------------------------
__global__ __launch_bounds__(256) void gate_kernel(const f16* __restrict__ o,
                                                   const f16* __restrict__ qkvz,
                                                   const float* __restrict__ norm_w,
                                                   f16* __restrict__ y) {
    int token = blockIdx.x;  // b*2048 + s
    int tid = threadIdx.x;
    int hv = tid >> 3, part = tid & 7;
    int dv0 = part * 16;
    const f16* orow = o + ((long)token * 32 + hv) * 128 + dv0;
    long zcol = (long)(hv >> 1) * 768 + 512 + (hv & 1) * 128 + dv0;
    const f16* zrow = qkvz + (long)token * 12288 + zcol;
    float yv[16];
    float ss = 0.f;
#pragma unroll
    for (int i = 0; i < 16; ++i) {
        float ov = (float)orow[i];
        float zv = (float)zrow[i];
        float gt = zv / (1.f + expf(-zv));
        float v = ov * gt;
        yv[i] = v;
        ss += v * v;
    }
    ss += __shfl_xor(ss, 1); ss += __shfl_xor(ss, 2); ss += __shfl_xor(ss, 4);
    float scale = rsqrtf(ss * (1.f / 128.f) + 1e-6f);
    f16* yrow = y + (long)token * 4096 + hv * 128 + dv0;
#pragma unroll
    for (int i = 0; i < 16; ++i) yrow[i] = (f16)(yv[i] * scale * norm_w[dv0 + i]);
}

// ------------------------------------------------------------------
// Workspace (242 MB, time-aliased):
//   [0,96)        qkvz16           (gemm1 -> gate)
//   [96,112)      x16              (prep -> gemm1)
//   [112,160)     WT               (prep -> gemm1)
//   [96,128)      ob f16           (scan -> gate)   — over dead x16+part of WT
//   [128,132)     scal f32 4MB     (cross -> scan)  — over dead WT
//   [160,176)     WTo              (prep -> gemm2)
//   [176,240)     qh/kh/vh         (conv -> scan); [176,208) reused as y16
//   [240,242)     bab/egb/btb
// ------------------------------------------------------------------
extern "C" void kernel_launch(void* const* d_in, const int* in_sizes, int n_in,
                              void* d_out, int out_size, void* d_ws, size_t ws_size,
                              hipStream_t stream) {
    const float* x       = (const float*)d_in[0];
    const float* w_qkvz  = (const float*)d_in[1];
    const float* w_ba    = (const float*)d_in[2];
    const float* conv_w  = (const float*)d_in[3];
    const float* conv_b  = (const float*)d_in[4];
    const float* a_log   = (const float*)d_in[5];
    const float* dt_bias = (const float*)d_in[6];
    const float* norm_w  = (const float*)d_in[7];
    const float* w_o     = (const float*)d_in[8];
    float* out = (float*)d_out;

    char* ws = (char*)d_ws;
    const size_t MB = 1024 * 1024;
    f16*   qkvz16 = (f16*)ws;                      // 96 MB
    f16*   x16    = (f16*)(ws + 96 * MB);          // 16 MB
    f16*   WT     = (f16*)(ws + 112 * MB);         // 48 MB
    f16*   ob     = (f16*)(ws + 96 * MB);          // 32 MB (after gemm1)
    float* scal   = (float*)(ws + 128 * MB);       // 4 MB (after gemm1)
    f16*   WTo    = (f16*)(ws + 160 * MB);         // 16 MB
    f16*   qh     = (f16*)(ws + 176 * MB);         // 16 MB
    f16*   kh     = (f16*)(ws + 192 * MB);         // 16 MB
    f16*   vh     = (f16*)(ws + 208 * MB);         // 32 MB
    f16*   y16    = (f16*)(ws + 176 * MB);         // 32 MB (after scan)
    float* bab    = (float*)(ws + 240 * MB);       // 1 MB
    float* egb    = (float*)(ws + 241 * MB);       // 0.5 MB
    float* btb    = (float*)(ws + 241 * MB + 512 * 1024);  // 0.5 MB

    // prep
    cvt16_kernel<<<8192, 256, 0, stream>>>(x, x16, 4096 * 2048 / 4);
    transpose16_kernel<<<dim3(12288 / 64, 2048 / 64), 256, 0, stream>>>(w_qkvz, WT, 2048, 12288);
    transpose16_kernel<<<dim3(2048 / 64, 4096 / 64), 256, 0, stream>>>(w_o, WTo, 4096, 2048);

    // qkvz = x @ w_qkvz
    gemm16_kernel<1><<<dim3(12288 / 128, 4096 / 128), 256, 0, stream>>>(x16, WT, qkvz16, 4096, 12288, 2048);
    // ba = x @ w_ba
    ba_gemm_kernel<<<256, 256, 0, stream>>>(x, w_ba, bab);

    // conv + silu + l2norm
    conv_kernel<<<dim3(64, 64, 2), 256, 0, stream>>>(qkvz16, conv_w, conv_b, qh, kh, vh);
    // gate scalars
    gb_kernel<<<512, 256, 0, stream>>>(bab, a_log, dt_bias, egb, btb);
    // per-group cross coefficients
    cross_kernel<<<8192, 256, 0, stream>>>(qh, kh, egb, btb, scal);

    // 4-step blocked delta scan
    scan_kernel<<<256, 256, 0, stream>>>(qh, kh, vh, scal, ob);

    // gating + rmsnorm -> y16
    gate_kernel<<<4096, 256, 0, stream>>>(ob, qkvz16, norm_w, y16);

    // out = y @ w_o
    gemm16_kernel<0><<<dim3(2048 / 128, 4096 / 128), 256, 0, stream>>>(y16, WTo, out, 4096, 2048, 4096);
}